// Round 6
// baseline (1758.083 us; speedup 1.0000x reference)
//
#include <hip/hip_runtime.h>

#define EPS_F 1e-6f

typedef float f32x4 __attribute__((ext_vector_type(4)));

// DIAGNOSTIC ROUND: same math/stores as the 171us round-1 kernel, but the
// 4 output stores are re-issued `reps` times (same addresses, same values --
// output stays correct and deterministic). Purpose: push this dispatch past
// the ~320us poison-fills so rocprof top-5 finally shows OUR FETCH/WRITE and
// discriminates write-allocate-fetch vs no-allocate vs write-through.
__global__ __launch_bounds__(256) void mueller_kernel(
    const float* __restrict__ cos_theta_i,
    const float* __restrict__ eta_arr,
    f32x4* __restrict__ out, int n, int reps)
{
    int i = blockIdx.x * blockDim.x + threadIdx.x;
    if (i >= n) return;

    float ci   = cos_theta_i[i];
    float eta  = eta_arr[i];
    float rcp_eta = 1.0f / eta;
    bool  outside = (ci >= 0.0f);
    float eta_it = outside ? eta : rcp_eta;
    float eta_ti = outside ? rcp_eta : eta;

    float cts    = 1.0f - eta_ti * eta_ti * (1.0f - ci * ci);
    float ci_abs = fabsf(ci);

    float x   = cts + EPS_F;
    float sgn = (cts >= 0.0f) ? 1.0f : -1.0f;
    float ctt_re, ctt_im;
    if (x >= 0.0f) { ctt_re = sqrtf(x) * sgn;  ctt_im = 0.0f; }
    else           { ctt_re = 0.0f;            ctt_im = sqrtf(-x) * sgn; }

    float A    = ci_abs;
    float u_re = eta_it * ctt_re;
    float u_im = eta_it * ctt_im;
    float ds2  = (A + u_re) * (A + u_re) + u_im * u_im;
    float inv_ds = 1.0f / ds2;
    float as_re = (A * A - u_re * u_re - u_im * u_im) * inv_ds;
    float as_im = (-2.0f * A * u_im) * inv_ds;

    float B    = eta_it * ci_abs;
    float dp2  = (B + ctt_re) * (B + ctt_re) + ctt_im * ctt_im;
    float inv_dp = 1.0f / dp2;
    float ap_re = (B * B - ctt_re * ctt_re - ctt_im * ctt_im) * inv_dp;
    float ap_im = (-2.0f * B * ctt_im) * inv_dp;

    if (eta == 1.0f || eta == 0.0f) {
        as_re = as_im = ap_re = ap_im = 0.0f;
    }

    float r_s  = as_re * as_re + as_im * as_im;
    float r_p  = ap_re * ap_re + ap_im * ap_im;
    float prod = r_p * r_s;

    float s    = sqrtf(prod + EPS_F);
    float norm = (prod == 0.0f) ? 0.0f : 1.0f / s;
    float cos_d = (ap_re * as_re + ap_im * as_im) * norm;
    float sin_d = (ap_im * as_re - ap_re * as_im) * norm;

    float a = 0.5f * (r_s + r_p);
    float b = 0.5f * (r_s - r_p);
    float cc = s * cos_d;
    float cs = s * sin_d;

    f32x4 r0 = {a,    b,    0.0f, 0.0f};
    f32x4 r1 = {b,    a,    0.0f, 0.0f};
    f32x4 r2 = {0.0f, 0.0f, cc,   -cs };
    f32x4 r3 = {0.0f, 0.0f, cs,   cc  };

    f32x4* o = out + (size_t)i * 4;
    for (int j = 0; j < reps; ++j) {
        o[0] = r0;
        o[1] = r1;
        o[2] = r2;
        o[3] = r3;
        // opaque barrier: stores of iteration j may be observed -> no DSE,
        // each iteration re-issues the 4 global_store_dwordx4.
        asm volatile("" ::: "memory");
    }
}

extern "C" void kernel_launch(void* const* d_in, const int* in_sizes, int n_in,
                              void* d_out, int out_size, void* d_ws, size_t ws_size,
                              hipStream_t stream) {
    const float* ci  = (const float*)d_in[0];
    const float* eta = (const float*)d_in[1];
    f32x4* out = (f32x4*)d_out;
    int n = in_sizes[0];
    int block = 256;
    int grid = (n + block - 1) / block;
    mueller_kernel<<<grid, block, 0, stream>>>(ci, eta, out, n, 12);
}

// Round 7
// 230.040 us; speedup vs baseline: 7.6425x; 7.6425x over previous
//
#include <hip/hip_runtime.h>

#define EPS_F 1e-6f

typedef float f32x4 __attribute__((ext_vector_type(4)));

__device__ __forceinline__ void mueller_vals(float ci, float eta,
                                             float& a, float& b,
                                             float& cc, float& cs)
{
    float rcp_eta = 1.0f / eta;
    bool  outside = (ci >= 0.0f);
    float eta_it = outside ? eta : rcp_eta;
    float eta_ti = outside ? rcp_eta : eta;

    float cts    = 1.0f - eta_ti * eta_ti * (1.0f - ci * ci);
    float ci_abs = fabsf(ci);

    // sqrtz: complex sqrt of (cts + EPS + 0j), then mulsign by sign(cts)
    float x   = cts + EPS_F;
    float sgn = (cts >= 0.0f) ? 1.0f : -1.0f;
    float ctt_re, ctt_im;
    if (x >= 0.0f) { ctt_re = sqrtf(x) * sgn;  ctt_im = 0.0f; }
    else           { ctt_re = 0.0f;            ctt_im = sqrtf(-x) * sgn; }

    float A    = ci_abs;
    float u_re = eta_it * ctt_re;
    float u_im = eta_it * ctt_im;
    float ds2  = (A + u_re) * (A + u_re) + u_im * u_im;
    float inv_ds = 1.0f / ds2;
    float as_re = (A * A - u_re * u_re - u_im * u_im) * inv_ds;
    float as_im = (-2.0f * A * u_im) * inv_ds;

    float B    = eta_it * ci_abs;
    float dp2  = (B + ctt_re) * (B + ctt_re) + ctt_im * ctt_im;
    float inv_dp = 1.0f / dp2;
    float ap_re = (B * B - ctt_re * ctt_re - ctt_im * ctt_im) * inv_dp;
    float ap_im = (-2.0f * B * ctt_im) * inv_dp;

    if (eta == 1.0f || eta == 0.0f) {     // dead for these inputs; fidelity
        as_re = as_im = ap_re = ap_im = 0.0f;
    }

    float r_s  = as_re * as_re + as_im * as_im;
    float r_p  = ap_re * ap_re + ap_im * ap_im;
    float prod = r_p * r_s;

    float s    = sqrtf(prod + EPS_F);     // c >= 1e-3 here; c==0 guard dead
    float norm = (prod == 0.0f) ? 0.0f : 1.0f / s;
    float cos_d = (ap_re * as_re + ap_im * as_im) * norm;
    float sin_d = (ap_im * as_re - ap_re * as_im) * norm;

    a  = 0.5f * (r_s + r_p);
    b  = 0.5f * (r_s - r_p);
    cc = s * cos_d;
    cs = s * sin_d;
}

// fillBuffer-shaped: small persistent grid, grid-stride over rays.
// ~2048 waves, each sweeping a long sequential output stream, instead of
// 131k short-lived waves spraying 4KB bursts across the address space.
__global__ __launch_bounds__(256) void mueller_kernel(
    const float* __restrict__ ci_p,
    const float* __restrict__ eta_p,
    f32x4* __restrict__ out, int n, int stride)
{
    int g = blockIdx.x * blockDim.x + threadIdx.x;
    for (int r = g; r < n; r += stride) {
        float a, b, cc, cs;
        mueller_vals(ci_p[r], eta_p[r], a, b, cc, cs);
        f32x4* o = out + (size_t)r * 4;
        o[0] = (f32x4){a,    b,    0.0f, 0.0f};
        o[1] = (f32x4){b,    a,    0.0f, 0.0f};
        o[2] = (f32x4){0.0f, 0.0f, cc,   -cs };
        o[3] = (f32x4){0.0f, 0.0f, cs,   cc  };
    }
}

extern "C" void kernel_launch(void* const* d_in, const int* in_sizes, int n_in,
                              void* d_out, int out_size, void* d_ws, size_t ws_size,
                              hipStream_t stream) {
    const float* ci  = (const float*)d_in[0];
    const float* eta = (const float*)d_in[1];
    f32x4* out = (f32x4*)d_out;
    int n = in_sizes[0];
    int block = 256;
    int grid = 512;                    // 2048 waves, 8/CU: few long streams
    int stride = grid * block;
    mueller_kernel<<<grid, block, 0, stream>>>(ci, eta, out, n, stride);
}

// Round 8
// 108.414 us; speedup vs baseline: 16.2163x; 2.1219x over previous
//
#include <hip/hip_runtime.h>

#define EPS_F 1e-6f

typedef float f32x4 __attribute__((ext_vector_type(4)));

__device__ __forceinline__ void mueller_vals(float ci, float eta,
                                             float& a, float& b,
                                             float& cc, float& cs)
{
    float rcp_eta = 1.0f / eta;
    bool  outside = (ci >= 0.0f);
    float eta_it = outside ? eta : rcp_eta;
    float eta_ti = outside ? rcp_eta : eta;

    float cts    = 1.0f - eta_ti * eta_ti * (1.0f - ci * ci);
    float ci_abs = fabsf(ci);

    // sqrtz: complex sqrt of (cts + EPS + 0j), then mulsign by sign(cts)
    float x   = cts + EPS_F;
    float sgn = (cts >= 0.0f) ? 1.0f : -1.0f;
    float ctt_re, ctt_im;
    if (x >= 0.0f) { ctt_re = sqrtf(x) * sgn;  ctt_im = 0.0f; }
    else           { ctt_re = 0.0f;            ctt_im = sqrtf(-x) * sgn; }

    float A    = ci_abs;
    float u_re = eta_it * ctt_re;
    float u_im = eta_it * ctt_im;
    float ds2  = (A + u_re) * (A + u_re) + u_im * u_im;
    float inv_ds = 1.0f / ds2;
    float as_re = (A * A - u_re * u_re - u_im * u_im) * inv_ds;
    float as_im = (-2.0f * A * u_im) * inv_ds;

    float B    = eta_it * ci_abs;
    float dp2  = (B + ctt_re) * (B + ctt_re) + ctt_im * ctt_im;
    float inv_dp = 1.0f / dp2;
    float ap_re = (B * B - ctt_re * ctt_re - ctt_im * ctt_im) * inv_dp;
    float ap_im = (-2.0f * B * ctt_im) * inv_dp;

    if (eta == 1.0f || eta == 0.0f) {     // dead for these inputs; fidelity
        as_re = as_im = ap_re = ap_im = 0.0f;
    }

    float r_s  = as_re * as_re + as_im * as_im;
    float r_p  = ap_re * ap_re + ap_im * ap_im;
    float prod = r_p * r_s;

    float s    = sqrtf(prod + EPS_F);     // c >= 1e-3 here; c==0 guard dead
    float norm = (prod == 0.0f) ? 0.0f : 1.0f / s;
    float cos_d = (ap_re * as_re + ap_im * as_im) * norm;
    float sin_d = (ap_im * as_re - ap_re * as_im) * norm;

    a  = 0.5f * (r_s + r_p);
    b  = 0.5f * (r_s - r_p);
    cc = s * cos_d;
    cs = s * sin_d;
}

// Phase 1: 256 rays/block -> (a,b,cc,cs) in LDS.
// Phase 2: sweep the block's 16KB output with dword stores: each wave-instr
// writes 64 consecutive dwords = one dense 256B span (4 cache lines), the
// exact transaction shape fillBufferAligned sustains 6.7 TB/s with.
__global__ __launch_bounds__(256) void mueller_kernel(
    const float* __restrict__ ci_p,
    const float* __restrict__ eta_p,
    float* __restrict__ out, int n)
{
    __shared__ f32x4 vals[256];

    int t    = threadIdx.x;
    int ray0 = blockIdx.x << 8;
    int ray  = ray0 + t;

    if (ray < n) {
        float a, b, cc, cs;
        mueller_vals(ci_p[ray], eta_p[ray], a, b, cc, cs);
        vals[t] = (f32x4){a, b, cc, cs};
    }
    __syncthreads();

    // Fixed per-thread elem role within the 4x4 matrix (d % 16):
    // value = mx*a + my*b + mz*cc + mw*cs
    int elem = t & 15;
    float mx = (elem == 0 || elem == 5)  ? 1.0f : 0.0f;
    float my = (elem == 1 || elem == 4)  ? 1.0f : 0.0f;
    float mz = (elem == 10 || elem == 15) ? 1.0f : 0.0f;
    float mw = (elem == 14) ? 1.0f : ((elem == 11) ? -1.0f : 0.0f);

    float* obase = out + ((size_t)ray0 << 4);

    if (ray0 + 256 <= n) {                 // full block: unguarded
        #pragma unroll
        for (int k = 0; k < 16; ++k) {
            int d  = t + (k << 8);         // dword index in block region
            f32x4 v = vals[d >> 4];        // 16-way broadcast, conflict-free
            obase[d] = mx * v.x + my * v.y + mz * v.z + mw * v.w;
        }
    } else {                               // tail block: guarded
        for (int k = 0; k < 16; ++k) {
            int d  = t + (k << 8);
            int rl = d >> 4;
            if (ray0 + rl < n) {
                f32x4 v = vals[rl];
                obase[d] = mx * v.x + my * v.y + mz * v.z + mw * v.w;
            }
        }
    }
}

extern "C" void kernel_launch(void* const* d_in, const int* in_sizes, int n_in,
                              void* d_out, int out_size, void* d_ws, size_t ws_size,
                              hipStream_t stream) {
    const float* ci  = (const float*)d_in[0];
    const float* eta = (const float*)d_in[1];
    float* out = (float*)d_out;
    int n = in_sizes[0];
    int block = 256;
    int grid = (n + block - 1) / block;    // 256 rays per block
    mueller_kernel<<<grid, block, 0, stream>>>(ci, eta, out, n);
}

// Round 9
// 104.901 us; speedup vs baseline: 16.7595x; 1.0335x over previous
//
#include <hip/hip_runtime.h>

#define EPS_F 1e-6f

__device__ __forceinline__ void mueller_vals(float ci, float eta,
                                             float& a, float& b,
                                             float& cc, float& cs)
{
    float rcp_eta = 1.0f / eta;
    bool  outside = (ci >= 0.0f);
    float eta_it = outside ? eta : rcp_eta;
    float eta_ti = outside ? rcp_eta : eta;

    float cts    = 1.0f - eta_ti * eta_ti * (1.0f - ci * ci);
    float ci_abs = fabsf(ci);

    // sqrtz: complex sqrt of (cts + EPS + 0j), then mulsign by sign(cts)
    float x   = cts + EPS_F;
    float sgn = (cts >= 0.0f) ? 1.0f : -1.0f;
    float ctt_re, ctt_im;
    if (x >= 0.0f) { ctt_re = sqrtf(x) * sgn;  ctt_im = 0.0f; }
    else           { ctt_re = 0.0f;            ctt_im = sqrtf(-x) * sgn; }

    float A    = ci_abs;
    float u_re = eta_it * ctt_re;
    float u_im = eta_it * ctt_im;
    float ds2  = (A + u_re) * (A + u_re) + u_im * u_im;
    float inv_ds = 1.0f / ds2;
    float as_re = (A * A - u_re * u_re - u_im * u_im) * inv_ds;
    float as_im = (-2.0f * A * u_im) * inv_ds;

    float B    = eta_it * ci_abs;
    float dp2  = (B + ctt_re) * (B + ctt_re) + ctt_im * ctt_im;
    float inv_dp = 1.0f / dp2;
    float ap_re = (B * B - ctt_re * ctt_re - ctt_im * ctt_im) * inv_dp;
    float ap_im = (-2.0f * B * ctt_im) * inv_dp;

    if (eta == 1.0f || eta == 0.0f) {     // dead for these inputs; fidelity
        as_re = as_im = ap_re = ap_im = 0.0f;
    }

    float r_s  = as_re * as_re + as_im * as_im;
    float r_p  = ap_re * ap_re + ap_im * ap_im;
    float prod = r_p * r_s;

    float s    = sqrtf(prod + EPS_F);     // c >= 1e-3 here; c==0 guard dead
    float norm = (prod == 0.0f) ? 0.0f : 1.0f / s;
    float cos_d = (ap_re * as_re + ap_im * as_im) * norm;
    float sin_d = (ap_im * as_re - ap_re * as_im) * norm;

    a  = 0.5f * (r_s + r_p);
    b  = 0.5f * (r_s - r_p);
    cc = s * cos_d;
    cs = s * sin_d;
}

// Phase 1: 256 rays/block -> full 16-dword matrix expanded into LDS
//          (row stride 17 dwords: 17 coprime 32 -> conflict-free writes).
// Phase 2: pure dword sweep of the block's 16KB region:
//          ds_read_b32 + global_store_dword per output dword (issue-lean),
//          each wave-store = 64 consecutive dwords = 4 dense lines (the
//          transaction shape proven fast in round 8).
__global__ __launch_bounds__(256) void mueller_kernel(
    const float* __restrict__ ci_p,
    const float* __restrict__ eta_p,
    float* __restrict__ out, int n)
{
    __shared__ float lds[256 * 17];

    int t    = threadIdx.x;
    int ray0 = blockIdx.x << 8;
    int ray  = ray0 + t;

    if (ray < n) {
        float a, b, cc, cs;
        mueller_vals(ci_p[ray], eta_p[ray], a, b, cc, cs);
        float v[16] = {a,    b,    0.0f, 0.0f,
                       b,    a,    0.0f, 0.0f,
                       0.0f, 0.0f, cc,   -cs,
                       0.0f, 0.0f, cs,   cc  };
        int wb = t * 17;
        #pragma unroll
        for (int e = 0; e < 16; ++e) lds[wb + e] = v[e];
    }
    __syncthreads();

    // dword d = t + k*256 of the block region; ray-local rl = d>>4, elem = t&15.
    int   rbase = (t >> 4) * 17 + (t & 15);           // += 272 per k
    float* ob   = out + ((size_t)ray0 << 4) + t;      // += 256 per k

    if (ray0 + 256 <= n) {                            // full block
        #pragma unroll
        for (int k = 0; k < 16; ++k)
            ob[k << 8] = lds[rbase + k * 272];
    } else {                                          // tail block
        for (int k = 0; k < 16; ++k) {
            int rl = (t >> 4) + (k << 4);
            if (ray0 + rl < n)
                ob[k << 8] = lds[rbase + k * 272];
        }
    }
}

extern "C" void kernel_launch(void* const* d_in, const int* in_sizes, int n_in,
                              void* d_out, int out_size, void* d_ws, size_t ws_size,
                              hipStream_t stream) {
    const float* ci  = (const float*)d_in[0];
    const float* eta = (const float*)d_in[1];
    float* out = (float*)d_out;
    int n = in_sizes[0];
    int block = 256;
    int grid = (n + block - 1) / block;    // 256 rays per block
    mueller_kernel<<<grid, block, 0, stream>>>(ci, eta, out, n);
}

// Round 10
// 104.697 us; speedup vs baseline: 16.7921x; 1.0019x over previous
//
#include <hip/hip_runtime.h>

#define EPS_F 1e-6f

typedef float f32x4 __attribute__((ext_vector_type(4)));

__device__ __forceinline__ void mueller_vals(float ci, float eta,
                                             float& a, float& b,
                                             float& cc, float& cs)
{
    float rcp_eta = 1.0f / eta;
    bool  outside = (ci >= 0.0f);
    float eta_it = outside ? eta : rcp_eta;
    float eta_ti = outside ? rcp_eta : eta;

    float cts    = 1.0f - eta_ti * eta_ti * (1.0f - ci * ci);
    float ci_abs = fabsf(ci);

    // sqrtz: complex sqrt of (cts + EPS + 0j), then mulsign by sign(cts)
    float x   = cts + EPS_F;
    float sgn = (cts >= 0.0f) ? 1.0f : -1.0f;
    float ctt_re, ctt_im;
    if (x >= 0.0f) { ctt_re = sqrtf(x) * sgn;  ctt_im = 0.0f; }
    else           { ctt_re = 0.0f;            ctt_im = sqrtf(-x) * sgn; }

    float A    = ci_abs;
    float u_re = eta_it * ctt_re;
    float u_im = eta_it * ctt_im;
    float ds2  = (A + u_re) * (A + u_re) + u_im * u_im;
    float inv_ds = 1.0f / ds2;
    float as_re = (A * A - u_re * u_re - u_im * u_im) * inv_ds;
    float as_im = (-2.0f * A * u_im) * inv_ds;

    float B    = eta_it * ci_abs;
    float dp2  = (B + ctt_re) * (B + ctt_re) + ctt_im * ctt_im;
    float inv_dp = 1.0f / dp2;
    float ap_re = (B * B - ctt_re * ctt_re - ctt_im * ctt_im) * inv_dp;
    float ap_im = (-2.0f * B * ctt_im) * inv_dp;

    if (eta == 1.0f || eta == 0.0f) {     // dead for these inputs; fidelity
        as_re = as_im = ap_re = ap_im = 0.0f;
    }

    float r_s  = as_re * as_re + as_im * as_im;
    float r_p  = ap_re * ap_re + ap_im * ap_im;
    float prod = r_p * r_s;

    float s    = sqrtf(prod + EPS_F);     // c >= 1e-3 here; c==0 guard dead
    float norm = (prod == 0.0f) ? 0.0f : 1.0f / s;
    float cos_d = (ap_re * as_re + ap_im * as_im) * norm;
    float sin_d = (ap_im * as_re - ap_re * as_im) * norm;

    a  = 0.5f * (r_s + r_p);
    b  = 0.5f * (r_s - r_p);
    cc = s * cos_d;
    cs = s * sin_d;
}

// Phase 1: 256 rays/block -> ONE ds_write_b128 per thread: {a,b,cc,cs}.
// Phase 2: dword sweep of the block's 16KB region (4-dense-line wave stores,
//          the round-8 winning shape): ds_read_b32 of the needed component
//          (16 distinct dwords/wave -> 16 banks, conflict-free; same-address
//          lanes broadcast) * per-thread constant m in {+1,-1,0}.
__global__ __launch_bounds__(256) void mueller_kernel(
    const float* __restrict__ ci_p,
    const float* __restrict__ eta_p,
    float* __restrict__ out, int n)
{
    __shared__ float lds[256 * 4];

    int t    = threadIdx.x;
    int ray0 = blockIdx.x << 8;
    int ray  = ray0 + t;

    if (ray < n) {
        float a, b, cc, cs;
        mueller_vals(ci_p[ray], eta_p[ray], a, b, cc, cs);
        *reinterpret_cast<f32x4*>(&lds[t << 2]) = (f32x4){a, b, cc, cs};
    }
    __syncthreads();

    // Per-thread fixed role: elem e = t&15 of the 4x4 row-major matrix
    //   [a b 0 0; b a 0 0; 0 0 cc -cs; 0 0 cs cc]
    // value = m * lds[ray][comp]
    int   e    = t & 15;
    int   comp = ((e >> 3) << 1) + ((e & 1) ^ ((e >> 2) & 1));
    bool  nz   = (((e >> 1) & 1) == ((e >> 3) & 1));
    float m    = nz ? ((e == 11) ? -1.0f : 1.0f) : 0.0f;

    int    lbase = ((t >> 4) << 2) + comp;            // dword idx; += 64 per k
    float* ob    = out + ((size_t)ray0 << 4) + t;     // += 256 per k

    if (ray0 + 256 <= n) {                            // full block
        #pragma unroll
        for (int k = 0; k < 16; ++k)
            ob[k << 8] = m * lds[lbase + (k << 6)];
    } else {                                          // tail block
        for (int k = 0; k < 16; ++k) {
            int rl = (t >> 4) + (k << 4);
            if (ray0 + rl < n)
                ob[k << 8] = m * lds[lbase + (k << 6)];
        }
    }
}

extern "C" void kernel_launch(void* const* d_in, const int* in_sizes, int n_in,
                              void* d_out, int out_size, void* d_ws, size_t ws_size,
                              hipStream_t stream) {
    const float* ci  = (const float*)d_in[0];
    const float* eta = (const float*)d_in[1];
    float* out = (float*)d_out;
    int n = in_sizes[0];
    int block = 256;
    int grid = (n + block - 1) / block;    // 256 rays per block
    mueller_kernel<<<grid, block, 0, stream>>>(ci, eta, out, n);
}